// Round 13
// baseline (244.047 us; speedup 1.0000x reference)
//
#include <hip/hip_runtime.h>
#include <hip/hip_bf16.h>

#define BB 16
#define NN 64
#define PREVN 6
#define PREDN 30
#define HH 256
#define EE 4032              // NN*(NN-1)
#define EROWS (BB*EE)        // 64512
#define NROWS (BB*NN)        // 1024

typedef short short8 __attribute__((ext_vector_type(8)));
typedef float f32x4 __attribute__((ext_vector_type(4)));

// ---- f32 workspace layout (float element offsets) ----
enum : int {
  OFF_STATS_E = 0,       // 1024: [0:256]=sum [256:512]=sumsq
  OFF_STATS_M = 1024,    // 1024
  OFF_XRS     = 2048,    // 262144 f32 slots = 524288 bf16: XR ++ XS (1024x256 each)
  OFF_SACC    = 264192,  // 1024*256 f32 receiver sums
  OFF_TACC    = 526336,  // 1024*256 f32 sender sums
  F32_END     = 788480
};
// ---- bf16 area (element offsets within wb = (bf16*)(ws + F32_END)) ----
enum : size_t {
  BO_W1TE  = 0,          // 256*512 (n2e W1^T)
  BO_W2TE  = 131072,     // 256*256
  BO_W1TN  = 196608,     // 256*512 (e2n W1^T)
  BO_W2TN  = 327680,     // 256*256
  BO_WFT   = 393216,     // 256*512 (W_fuse^T)
  BO_WPT   = 524288,     // 64*256  (W_pred^T, zero-padded cols 60..63)
  BO_M2    = 540672      // 1024*256
};

// fast ELU: exp(x)-1 via v_exp_f32; abs err ~1e-7 near 0- (invisible at bf16)
__device__ __forceinline__ float eluf(float v) { return v > 0.f ? v : __expf(v) - 1.f; }

// async global -> LDS, 16 B per lane; LDS dest = wave-uniform base + lane*16
__device__ __forceinline__ void gl2lds16(const void* g, void* l) {
  __builtin_amdgcn_global_load_lds(
      (const __attribute__((address_space(1))) void*)g,
      (__attribute__((address_space(3))) void*)l, 16, 0, 0);
}

// compute one x-embed element: row rr (global), col
__device__ __forceinline__ float xembed(const float* __restrict__ centers,
                                        const float* __restrict__ Wt,
                                        const float* __restrict__ bt,
                                        int rr, int col) {
  const float* c = centers + rr * 12;
  float acc = bt[col];
  #pragma unroll
  for (int t = 0; t < 5; ++t) {
    float dx = c[(t+1)*2 + 0] - c[t*2 + 0];
    float dy = c[(t+1)*2 + 1] - c[t*2 + 1];
    acc += dx * Wt[(2 + 2*t)*HH + col] + dy * Wt[(3 + 2*t)*HH + col];
  }
  return acc;
}

// ================= prep: transposes + wpt + zero stats/Sacc/Tacc ===============
struct PrepArgs {
  const float *n2e_W1, *n2e_W2, *e2n_W1, *e2n_W2, *W_fuse, *W_pred;
  float* ws;                       // stats @0, Sacc/Tacc zeroed too
  __hip_bfloat16 *w1te, *w2te, *w1tn, *w2tn, *wft, *wpt;
};

__global__ __launch_bounds__(256) void k_prep(PrepArgs a) {
  __shared__ float t[64][65];
  const int bid = blockIdx.x, tid = threadIdx.x;
  if (bid < 128) {                 // LDS-tiled W transposes (f32 KxN -> bf16 NxK)
    const float* W; __hip_bfloat16* WT; int K, lb;
    if (bid < 32)      { W = a.n2e_W1; WT = a.w1te; K = 512; lb = bid; }
    else if (bid < 48) { W = a.n2e_W2; WT = a.w2te; K = 256; lb = bid - 32; }
    else if (bid < 80) { W = a.e2n_W1; WT = a.w1tn; K = 512; lb = bid - 48; }
    else if (bid < 96) { W = a.e2n_W2; WT = a.w2tn; K = 256; lb = bid - 80; }
    else               { W = a.W_fuse; WT = a.wft;  K = 512; lb = bid - 96; }
    int KB = K / 64;
    int k0 = (lb % KB) * 64, n0 = (lb / KB) * 64;
    int tx = tid & 63, ty = tid >> 6;
    #pragma unroll
    for (int i = 0; i < 16; ++i)
      t[ty + i*4][tx] = W[(size_t)(k0 + ty + i*4) * 256 + n0 + tx];
    __syncthreads();
    #pragma unroll
    for (int i = 0; i < 16; ++i)
      WT[(size_t)(n0 + ty + i*4) * K + k0 + tx] = __float2bfloat16(t[tx][ty + i*4]);
  } else if (bid < 192) {          // W_pred (256x60) -> WpT (64x256, zero-padded)
    int idx = (bid - 128) * 256 + tid;
    int c = idx >> 8, k = idx & 255;
    a.wpt[idx] = __float2bfloat16(c < 60 ? a.W_pred[k * 60 + c] : 0.f);
  } else if (bid < 200) {          // zero stats (2048 floats)
    a.ws[(bid - 192) * 256 + tid] = 0.f;
  } else {                         // zero Sacc+Tacc: 524288 floats, float4
    int idx = (bid - 200) * 1024 + tid * 4;
    *reinterpret_cast<float4*>(a.ws + OFF_SACC + idx) = (float4){0.f, 0.f, 0.f, 0.f};
  }
}

// ---- XR = x @ W1_top + b1 ; XS = x @ W1_bot. grid 64 (32 rows/block) ----
__global__ __launch_bounds__(256) void k_xrs(
    const float* __restrict__ centers,
    const float* __restrict__ W_traj,
    const float* __restrict__ b_traj,
    const __hip_bfloat16* __restrict__ W1T,   // 256 x 512 n-major
    const float* __restrict__ b1,
    __hip_bfloat16* __restrict__ xrs) {       // XR ++ XS
  __shared__ alignas(16) __hip_bfloat16 xls[32][264];
  const int tid = threadIdx.x;
  const int w = tid >> 6, lane = tid & 63;
  const int m16 = lane & 15, quad = lane >> 4;
  const int ko = quad * 8;
  const int half = blockIdx.x >> 5;           // 0 = XR (+b1), 1 = XS
  const int row0 = (blockIdx.x & 31) * 32;
  const int colw = w * 64;
  __hip_bfloat16* dst = xrs + (size_t)half * 262144;

  #pragma unroll 4
  for (int r = 0; r < 32; ++r)
    xls[r][tid] = __float2bfloat16(xembed(centers, W_traj, b_traj, row0 + r, tid));
  __syncthreads();

  f32x4 acc[2][4];
  #pragma unroll
  for (int jt = 0; jt < 4; ++jt) {
    float bv = half ? 0.f : b1[colw + jt*16 + m16];
    #pragma unroll
    for (int mt = 0; mt < 2; ++mt) acc[mt][jt] = (f32x4){bv, bv, bv, bv};
  }
  #pragma unroll
  for (int ks = 0; ks < 8; ++ks) {
    short8 af[2], bf[4];
    #pragma unroll
    for (int mt = 0; mt < 2; ++mt)
      af[mt] = *reinterpret_cast<const short8*>(&xls[mt*16 + m16][ks*32 + ko]);
    #pragma unroll
    for (int jt = 0; jt < 4; ++jt)
      bf[jt] = *reinterpret_cast<const short8*>(
          W1T + (size_t)(colw + jt*16 + m16)*512 + half*256 + ks*32 + ko);
    #pragma unroll
    for (int mt = 0; mt < 2; ++mt)
      #pragma unroll
      for (int jt = 0; jt < 4; ++jt)
        acc[mt][jt] = __builtin_amdgcn_mfma_f32_16x16x32_bf16(af[mt], bf[jt],
                                                              acc[mt][jt], 0, 0, 0);
  }
  #pragma unroll
  for (int mt = 0; mt < 2; ++mt)
    #pragma unroll
    for (int jt = 0; jt < 4; ++jt)
      #pragma unroll
      for (int r = 0; r < 4; ++r)
        dst[(size_t)(row0 + mt*16 + quad*4 + r)*256 + colw + jt*16 + m16] =
            __float2bfloat16(acc[mt][jt][r]);
}

// ================= edge MLP: factored layer-1, atomic aggregation epilogue =====
// No e2 store: epilogue accumulates stats + receiver sums (Sacc) + sender sums
// (Tacc) via coalesced global f32 atomics (fire-and-forget).
__global__ __launch_bounds__(256, 2) void k_mlp6(
    const __hip_bfloat16* __restrict__ xrs,   // XR ++ XS
    const __hip_bfloat16* __restrict__ W2T,   // 256 x 256, n-major
    const float* __restrict__ b2,
    float* __restrict__ stats,
    float* __restrict__ Sacc,
    float* __restrict__ Tacc) {
  __shared__ alignas(16) char reg1[33792];    // [0,32768): XS[b]; [32768,33792): XR rows n0,n0+1
  __shared__ alignas(16) __hip_bfloat16 h1s[64][264];
  __shared__ int sd64[64];
  __shared__ int rcf[64];
  const int tid = threadIdx.x;
  const int w = tid >> 6, lane = tid & 63;
  const int m16 = lane & 15, quad = lane >> 4;
  const int ko = quad * 8;
  const int blk = blockIdx.x;                 // 1008
  const int bb = blk / 63, lb = blk - bb*63;
  const int n0 = (lb * 64) / 63;              // receivers are n0, n0+1
  const int colw = w * 64;

  // ---- stage XS[b] (32 KB = 32 segs x 1024 B) + 2 XR rows; index tables ----
  const char* xsb = (const char*)(xrs + 262144 + (size_t)bb*64*256);
  #pragma unroll
  for (int i = 0; i < 8; ++i) {
    int seg = w*8 + i;
    gl2lds16(xsb + seg*1024 + lane*16, reg1 + seg*1024);
  }
  if (w == 0)
    gl2lds16((const char*)(xrs + (size_t)(bb*64 + n0)*256) + lane*16, reg1 + 32768);
  if (tid < 64) {
    int e = lb*64 + tid;
    int rc = e / 63; int jj = e - rc*63;
    sd64[tid] = jj + (jj >= rc ? 1 : 0);
    rcf[tid]  = rc - n0;                      // 0 or 1
  }
  __syncthreads();

  // ---- h1 = elu(XR[rc] + XS[sd]) -> h1s ----
  {
    const int ty = tid >> 7;                  // rows ty*32 .. ty*32+31
    const int c2 = (tid & 127) * 2;           // col pair
    #pragma unroll 4
    for (int r2 = 0; r2 < 32; ++r2) {
      int r = ty*32 + r2;
      __hip_bfloat162 xa = *reinterpret_cast<const __hip_bfloat162*>(
          reg1 + 32768 + rcf[r]*512 + c2*2);
      __hip_bfloat162 xs2 = *reinterpret_cast<const __hip_bfloat162*>(
          reg1 + sd64[r]*512 + c2*2);
      __hip_bfloat162 o;
      o.x = __float2bfloat16(eluf(__bfloat162float(xa.x) + __bfloat162float(xs2.x)));
      o.y = __float2bfloat16(eluf(__bfloat162float(xa.y) + __bfloat162float(xs2.y)));
      *reinterpret_cast<__hip_bfloat162*>(&h1s[r][c2]) = o;
    }
  }
  __syncthreads();   // h1s complete

  // ---- layer 2: 64x256 @ 256x256, B direct from global (L2-hot 128 KB) ----
  f32x4 acc2[4][4];
  #pragma unroll
  for (int jt = 0; jt < 4; ++jt) {
    float bv = b2[colw + jt*16 + m16];
    #pragma unroll
    for (int mt = 0; mt < 4; ++mt) acc2[mt][jt] = (f32x4){bv, bv, bv, bv};
  }
  #pragma unroll
  for (int kt = 0; kt < 4; ++kt) {
    #pragma unroll
    for (int ks = 0; ks < 2; ++ks) {
      const int k0 = kt*64 + ks*32 + ko;
      short8 af[4], bf[4];
      #pragma unroll
      for (int jt = 0; jt < 4; ++jt)
        bf[jt] = *reinterpret_cast<const short8*>(
            W2T + (size_t)(colw + jt*16 + m16)*256 + k0);
      #pragma unroll
      for (int mt = 0; mt < 4; ++mt)
        af[mt] = *(const short8*)((const char*)h1s +
                     (size_t)(mt*16 + m16)*528 + k0*2);
      #pragma unroll
      for (int mt = 0; mt < 4; ++mt)
        #pragma unroll
        for (int jt = 0; jt < 4; ++jt)
          acc2[mt][jt] = __builtin_amdgcn_mfma_f32_16x16x32_bf16(af[mt], bf[jt],
                                                                 acc2[mt][jt], 0, 0, 0);
    }
  }
  __syncthreads();   // all h1 reads done before h1s is overwritten with h2

  // ---- ELU(h2) -> h1s ----
  #pragma unroll
  for (int mt = 0; mt < 4; ++mt)
    #pragma unroll
    for (int jt = 0; jt < 4; ++jt)
      #pragma unroll
      for (int r = 0; r < 4; ++r)
        h1s[mt*16 + quad*4 + r][colw + jt*16 + m16] =
            __float2bfloat16(eluf(acc2[mt][jt][r]));
  __syncthreads();

  // ---- fused stats + receiver/sender aggregation (coalesced atomics) ----
  {
    float s = 0.f, q = 0.f, sr0 = 0.f, sr1 = 0.f;
    float* TaccB = Tacc + (size_t)bb*64*256;
    #pragma unroll 8
    for (int r = 0; r < 64; ++r) {
      float v = __bfloat162float(h1s[r][tid]);
      s += v; q += v * v;
      if (rcf[r] == 0) sr0 += v; else sr1 += v;
      atomicAdd(&TaccB[sd64[r]*256 + tid], v);
    }
    atomicAdd(&stats[tid], s);
    atomicAdd(&stats[256 + tid], q);
    float* SaccB = Sacc + (size_t)bb*64*256;
    atomicAdd(&SaccB[n0*256 + tid], sr0);
    atomicAdd(&SaccB[(n0+1)*256 + tid], sr1);
  }
}

// ================= node MLP: A built inline from Sacc/Tacc + edge BN ==========
__global__ __launch_bounds__(256, 2) void k_mlp3n(
    const float* __restrict__ Sacc,
    const float* __restrict__ Tacc,
    const float* __restrict__ stE,
    const float* __restrict__ gamE,
    const float* __restrict__ betE,
    const __hip_bfloat16* __restrict__ W1T,   // 256 x 512, n-major
    const float* __restrict__ b1,
    const __hip_bfloat16* __restrict__ W2T,   // 256 x 256, n-major
    const float* __restrict__ b2,
    __hip_bfloat16* __restrict__ outp,        // m2
    float* __restrict__ stats) {
  __shared__ alignas(16) __hip_bfloat16 Wt[256 * 64];
  __shared__ alignas(16) __hip_bfloat16 h1s[16][264];
  __shared__ float bnA[256], bnC[256];
  const int tid = threadIdx.x;
  const int w = tid >> 6, lane = tid & 63;
  const int m16 = lane & 15, quad = lane >> 4;
  const int ko = quad * 8;
  const int row0 = blockIdx.x * 16;
  const int colw = w * 64;
  const int csub = lane >> 3, jl = lane & 7;
  const int jsrc = jl ^ csub;
  const int swz0 = ((quad)     ^ (m16 & 7)) * 16;
  const int swz1 = ((quad + 4) ^ (m16 & 7)) * 16;

  {  // edge BN affine (folded /63)
    const float inv = 1.f / (float)EROWS;
    float mean = stE[tid] * inv;
    float var  = fmaxf(stE[256 + tid] * inv - mean*mean, 0.f);
    float a = gamE[tid] * rsqrtf(var + 1e-5f);
    bnA[tid] = a * (1.f/63.f);
    bnC[tid] = betE[tid] - mean * a;
  }

  // builds lane's A-fragment for k0..k0+7 of row (row0+m16)
  auto afrag = [&](int k0) -> short8 {
    int g = row0 + m16;
    int kb = k0 & 255;
    const float* src = (k0 < 256) ? (Sacc + (size_t)g*256 + k0)
                                  : (Tacc + (size_t)g*256 + kb);
    float4 v0 = *reinterpret_cast<const float4*>(src);
    float4 v1 = *reinterpret_cast<const float4*>(src + 4);
    const float* vp0 = reinterpret_cast<const float*>(&v0);
    const float* vp1 = reinterpret_cast<const float*>(&v1);
    union { short8 s8; __hip_bfloat16 h[8]; } o;
    #pragma unroll
    for (int j = 0; j < 4; ++j) {
      o.h[j]     = __float2bfloat16(bnA[kb+j]   * vp0[j] + bnC[kb+j]);
      o.h[4 + j] = __float2bfloat16(bnA[kb+4+j] * vp1[j] + bnC[kb+4+j]);
    }
    return o.s8;
  };

  f32x4 acc[4];
  #pragma unroll
  for (int jt = 0; jt < 4; ++jt) {
    float bv = b1[colw + jt*16 + m16];
    acc[jt] = (f32x4){bv, bv, bv, bv};
  }
  __syncthreads();   // bnA/bnC ready
  for (int kt = 0; kt < 8; ++kt) {
    const int k0 = kt * 64;
    #pragma unroll
    for (int i = 0; i < 8; ++i) {
      const __hip_bfloat16* gp = W1T + (size_t)(colw + i*8 + csub) * 512 + k0 + jsrc*8;
      gl2lds16(gp, (char*)Wt + w*8192 + i*1024);
    }
    __syncthreads();
    #pragma unroll
    for (int ks = 0; ks < 2; ++ks) {
      const int sw = ks ? swz1 : swz0;
      short8 af = afrag(k0 + ks*32 + ko);
      short8 bf[4];
      #pragma unroll
      for (int jt = 0; jt < 4; ++jt)
        bf[jt] = *(const short8*)((const char*)Wt + (colw + jt*16 + m16)*128 + sw);
      #pragma unroll
      for (int jt = 0; jt < 4; ++jt)
        acc[jt] = __builtin_amdgcn_mfma_f32_16x16x32_bf16(af, bf[jt], acc[jt], 0, 0, 0);
    }
    __syncthreads();
  }
  #pragma unroll
  for (int jt = 0; jt < 4; ++jt)
    #pragma unroll
    for (int r = 0; r < 4; ++r)
      h1s[quad*4 + r][colw + jt*16 + m16] = __float2bfloat16(eluf(acc[jt][r]));
  __syncthreads();

  f32x4 acc2[4];
  #pragma unroll
  for (int jt = 0; jt < 4; ++jt) {
    float bv = b2[colw + jt*16 + m16];
    acc2[jt] = (f32x4){bv, bv, bv, bv};
  }
  #pragma unroll
  for (int kt = 0; kt < 4; ++kt) {
    #pragma unroll
    for (int ks = 0; ks < 2; ++ks) {
      const int k0 = kt*64 + ks*32 + ko;
      short8 af = *(const short8*)((const char*)h1s + (size_t)m16*528 + k0*2);
      short8 bf[4];
      #pragma unroll
      for (int jt = 0; jt < 4; ++jt)
        bf[jt] = *reinterpret_cast<const short8*>(
            W2T + (size_t)(colw + jt*16 + m16)*256 + k0);
      #pragma unroll
      for (int jt = 0; jt < 4; ++jt)
        acc2[jt] = __builtin_amdgcn_mfma_f32_16x16x32_bf16(af, bf[jt], acc2[jt], 0, 0, 0);
    }
  }
  __syncthreads();
  #pragma unroll
  for (int jt = 0; jt < 4; ++jt)
    #pragma unroll
    for (int r = 0; r < 4; ++r)
      h1s[quad*4 + r][colw + jt*16 + m16] = __float2bfloat16(eluf(acc2[jt][r]));
  __syncthreads();

  {
    float s = 0.f, q = 0.f;
    #pragma unroll 8
    for (int r = 0; r < 16; ++r) {
      float v = __bfloat162float(h1s[r][tid]);
      s += v; q += v * v;
    }
    atomicAdd(&stats[tid], s);
    atomicAdd(&stats[256 + tid], q);
  }
  #pragma unroll
  for (int i = 0; i < 2; ++i) {
    int u = i*256 + tid;
    int r = u >> 5, c = (u & 31) * 8;
    *reinterpret_cast<uint4*>(outp + (size_t)(row0 + r)*HH + c) =
        *reinterpret_cast<const uint4*>(&h1s[r][c]);
  }
}

// ---- head: 16-row blocks (grid 64), x recomputed in-kernel, BN(m2) inline ----
__global__ __launch_bounds__(256) void k_head2(
    const float* __restrict__ centers,
    const float* __restrict__ W_traj,
    const float* __restrict__ b_traj,
    const __hip_bfloat16* __restrict__ m2,
    const float* __restrict__ stM,
    const float* __restrict__ gam,
    const float* __restrict__ bet,
    const __hip_bfloat16* __restrict__ WfT,
    const float* __restrict__ bfv,
    const __hip_bfloat16* __restrict__ WpT,
    const float* __restrict__ bp,
    float* __restrict__ out) {
  __shared__ alignas(16) __hip_bfloat16 xs[16][264];
  __shared__ alignas(16) __hip_bfloat16 hs[16][264];
  __shared__ float rl[16][64];
  __shared__ float bnA[256], bnC[256];
  const int tid = threadIdx.x;
  const int w = tid >> 6, lane = tid & 63;
  const int m16 = lane & 15, quad = lane >> 4;
  const int ko = quad * 8;
  const int row0 = blockIdx.x * 16;
  const int colw = w * 64;

  {  // BN affine table
    const float inv = 1.f / (float)NROWS;
    float mean = stM[tid] * inv;
    float var  = fmaxf(stM[256 + tid] * inv - mean*mean, 0.f);
    float am = gam[tid] * rsqrtf(var + 1e-5f);
    bnA[tid] = am;
    bnC[tid] = bet[tid] - mean * am;
  }
  #pragma unroll
  for (int r = 0; r < 16; ++r)
    xs[r][tid] = __float2bfloat16(xembed(centers, W_traj, b_traj, row0 + r, tid));
  __syncthreads();

  // fuse: 16x512 @ 512x256
  f32x4 acc[4];
  #pragma unroll
  for (int jt = 0; jt < 4; ++jt) {
    float bv = bfv[colw + jt*16 + m16];
    acc[jt] = (f32x4){bv, bv, bv, bv};
  }
  #pragma unroll
  for (int ks = 0; ks < 16; ++ks) {
    short8 af;
    if (ks < 8) {
      af = *reinterpret_cast<const short8*>(&xs[m16][ks*32 + ko]);
    } else {
      int k0 = (ks - 8)*32 + ko;
      union { uint4 u; __hip_bfloat16 h[8]; } v;
      v.u = *reinterpret_cast<const uint4*>(m2 + (size_t)(row0 + m16)*256 + k0);
      union { short8 s8; __hip_bfloat16 h[8]; } o;
      #pragma unroll
      for (int j = 0; j < 8; ++j)
        o.h[j] = __float2bfloat16(bnA[k0+j] * __bfloat162float(v.h[j]) + bnC[k0+j]);
      af = o.s8;
    }
    short8 bf[4];
    #pragma unroll
    for (int jt = 0; jt < 4; ++jt)
      bf[jt] = *reinterpret_cast<const short8*>(
          WfT + (size_t)(colw + jt*16 + m16)*512 + ks*32 + ko);
    #pragma unroll
    for (int jt = 0; jt < 4; ++jt)
      acc[jt] = __builtin_amdgcn_mfma_f32_16x16x32_bf16(af, bf[jt], acc[jt], 0, 0, 0);
  }
  #pragma unroll
  for (int jt = 0; jt < 4; ++jt)
    #pragma unroll
    for (int r = 0; r < 4; ++r)
      hs[quad*4 + r][colw + jt*16 + m16] = __float2bfloat16(acc[jt][r]);
  __syncthreads();

  // pred: 16x256 @ 256x64 (wave 0)
  if (w == 0) {
    f32x4 acc2[4];
    #pragma unroll
    for (int jt = 0; jt < 4; ++jt) {
      int c = jt*16 + m16;
      float bv = (c < 60) ? bp[c] : 0.f;
      acc2[jt] = (f32x4){bv, bv, bv, bv};
    }
    #pragma unroll
    for (int ks = 0; ks < 8; ++ks) {
      short8 af = *reinterpret_cast<const short8*>(&hs[m16][ks*32 + ko]);
      short8 bf[4];
      #pragma unroll
      for (int jt = 0; jt < 4; ++jt)
        bf[jt] = *reinterpret_cast<const short8*>(
            WpT + (size_t)(jt*16 + m16)*256 + ks*32 + ko);
      #pragma unroll
      for (int jt = 0; jt < 4; ++jt)
        acc2[jt] = __builtin_amdgcn_mfma_f32_16x16x32_bf16(af, bf[jt], acc2[jt], 0, 0, 0);
    }
    #pragma unroll
    for (int jt = 0; jt < 4; ++jt) {
      int c = jt*16 + m16;
      #pragma unroll
      for (int r = 0; r < 4; ++r) {
        int lr = quad*4 + r;
        rl[lr][c] = acc2[jt][r];
        if (c < 60) out[(size_t)(row0 + lr)*60 + c] = acc2[jt][r];
      }
    }
  }
  __syncthreads();

  // cumsum
  if (tid < 32) {
    int lr = tid >> 1, xy = tid & 1;
    int grow = row0 + lr;
    float run = centers[(size_t)(grow*PREVN + 5)*2 + xy];
    #pragma unroll
    for (int p = 0; p < PREDN; ++p) {
      run += rl[lr][2*p + xy];
      out[61440 + (size_t)grow*60 + 2*p + xy] = run;
    }
  }
}

extern "C" void kernel_launch(void* const* d_in, const int* in_sizes, int n_in,
                              void* d_out, int out_size, void* d_ws, size_t ws_size,
                              hipStream_t stream) {
  const float* centers = (const float*)d_in[0];
  float* ws = (float*)d_ws;
  __hip_bfloat16* wb = (__hip_bfloat16*)(ws + F32_END);
  __hip_bfloat16* xrs = (__hip_bfloat16*)(ws + OFF_XRS);

  const float* W_traj = (const float*)d_in[3];
  const float* b_traj = (const float*)d_in[4];
  const float* n2e_b1 = (const float*)d_in[6];
  const float* n2e_b2 = (const float*)d_in[8];
  const float* n2e_g  = (const float*)d_in[9];
  const float* n2e_be = (const float*)d_in[10];
  const float* e2n_b1 = (const float*)d_in[12];
  const float* e2n_b2 = (const float*)d_in[14];
  const float* e2n_g  = (const float*)d_in[15];
  const float* e2n_be = (const float*)d_in[16];
  const float* b_fuse = (const float*)d_in[18];
  const float* b_pred = (const float*)d_in[20];

  PrepArgs pa;
  pa.n2e_W1 = (const float*)d_in[5];  pa.n2e_W2 = (const float*)d_in[7];
  pa.e2n_W1 = (const float*)d_in[11]; pa.e2n_W2 = (const float*)d_in[13];
  pa.W_fuse = (const float*)d_in[17]; pa.W_pred = (const float*)d_in[19];
  pa.ws = ws;
  pa.w1te = wb + BO_W1TE; pa.w2te = wb + BO_W2TE;
  pa.w1tn = wb + BO_W1TN; pa.w2tn = wb + BO_W2TN;
  pa.wft = wb + BO_WFT;   pa.wpt = wb + BO_WPT;

  k_prep<<<712, 256, 0, stream>>>(pa);
  k_xrs<<<64, 256, 0, stream>>>(centers, W_traj, b_traj, wb + BO_W1TE, n2e_b1, xrs);
  k_mlp6<<<EROWS/64, 256, 0, stream>>>(xrs, wb + BO_W2TE, n2e_b2,
                                       ws + OFF_STATS_E, ws + OFF_SACC, ws + OFF_TACC);
  k_mlp3n<<<NROWS/16, 256, 0, stream>>>(ws + OFF_SACC, ws + OFF_TACC,
                                        ws + OFF_STATS_E, n2e_g, n2e_be,
                                        wb + BO_W1TN, e2n_b1, wb + BO_W2TN, e2n_b2,
                                        wb + BO_M2, ws + OFF_STATS_M);
  k_head2<<<NROWS/16, 256, 0, stream>>>(centers, W_traj, b_traj, wb + BO_M2,
                                        ws + OFF_STATS_M, e2n_g, e2n_be,
                                        wb + BO_WFT, b_fuse, wb + BO_WPT, b_pred,
                                        (float*)d_out);
}

// Round 14
// 215.427 us; speedup vs baseline: 1.1329x; 1.1329x over previous
//
#include <hip/hip_runtime.h>
#include <hip/hip_bf16.h>

#define BB 16
#define NN 64
#define PREVN 6
#define PREDN 30
#define HH 256
#define EE 4032              // NN*(NN-1)
#define EROWS (BB*EE)        // 64512
#define NROWS (BB*NN)        // 1024

typedef short short8 __attribute__((ext_vector_type(8)));
typedef float f32x4 __attribute__((ext_vector_type(4)));

// ---- f32 workspace layout (float element offsets) ----
enum : int {
  OFF_STATS_E = 0,       // 1024: [0:256]=sum [256:512]=sumsq
  OFF_STATS_M = 1024,    // 1024
  OFF_XRS     = 2048,    // 262144 f32 slots = 524288 bf16: XR ++ XS
  OFF_SACC    = 264192,  // 1024*256 f32 receiver sums
  F32_END     = 526336
};
// ---- bf16 area (element offsets within wb = (bf16*)(ws + F32_END)) ----
enum : size_t {
  BO_W1TE  = 0,          // 256*512 (n2e W1^T)
  BO_W2TE  = 131072,     // 256*256
  BO_W1TN  = 196608,     // 256*512 (e2n W1^T)
  BO_W2TN  = 327680,     // 256*256
  BO_WFT   = 393216,     // 256*512 (W_fuse^T)
  BO_WPT   = 524288,     // 64*256  (W_pred^T, zero-padded cols 60..63)
  BO_NODES = 540672,     // 1024*512
  BO_M2    = 1064960,    // 1024*256
  BO_E2    = 1327104     // 64512*256
};

// fast ELU: exp(x)-1 via v_exp_f32; abs err ~1e-7 near 0- (invisible at bf16)
__device__ __forceinline__ float eluf(float v) { return v > 0.f ? v : __expf(v) - 1.f; }

// async global -> LDS, 16 B per lane; LDS dest = wave-uniform base + lane*16
__device__ __forceinline__ void gl2lds16(const void* g, void* l) {
  __builtin_amdgcn_global_load_lds(
      (const __attribute__((address_space(1))) void*)g,
      (__attribute__((address_space(3))) void*)l, 16, 0, 0);
}

// compute one x-embed element: row rr (global), col
__device__ __forceinline__ float xembed(const float* __restrict__ centers,
                                        const float* __restrict__ Wt,
                                        const float* __restrict__ bt,
                                        int rr, int col) {
  const float* c = centers + rr * 12;
  float acc = bt[col];
  #pragma unroll
  for (int t = 0; t < 5; ++t) {
    float dx = c[(t+1)*2 + 0] - c[t*2 + 0];
    float dy = c[(t+1)*2 + 1] - c[t*2 + 1];
    acc += dx * Wt[(2 + 2*t)*HH + col] + dy * Wt[(3 + 2*t)*HH + col];
  }
  return acc;
}

// ================= prep: transposes + wpt + zero stats/Sacc ====================
struct PrepArgs {
  const float *n2e_W1, *n2e_W2, *e2n_W1, *e2n_W2, *W_fuse, *W_pred;
  float* ws;
  __hip_bfloat16 *w1te, *w2te, *w1tn, *w2tn, *wft, *wpt;
};

__global__ __launch_bounds__(256) void k_prep(PrepArgs a) {
  __shared__ float t[64][65];
  const int bid = blockIdx.x, tid = threadIdx.x;
  if (bid < 128) {                 // LDS-tiled W transposes (f32 KxN -> bf16 NxK)
    const float* W; __hip_bfloat16* WT; int K, lb;
    if (bid < 32)      { W = a.n2e_W1; WT = a.w1te; K = 512; lb = bid; }
    else if (bid < 48) { W = a.n2e_W2; WT = a.w2te; K = 256; lb = bid - 32; }
    else if (bid < 80) { W = a.e2n_W1; WT = a.w1tn; K = 512; lb = bid - 48; }
    else if (bid < 96) { W = a.e2n_W2; WT = a.w2tn; K = 256; lb = bid - 80; }
    else               { W = a.W_fuse; WT = a.wft;  K = 512; lb = bid - 96; }
    int KB = K / 64;
    int k0 = (lb % KB) * 64, n0 = (lb / KB) * 64;
    int tx = tid & 63, ty = tid >> 6;
    #pragma unroll
    for (int i = 0; i < 16; ++i)
      t[ty + i*4][tx] = W[(size_t)(k0 + ty + i*4) * 256 + n0 + tx];
    __syncthreads();
    #pragma unroll
    for (int i = 0; i < 16; ++i)
      WT[(size_t)(n0 + ty + i*4) * K + k0 + tx] = __float2bfloat16(t[tx][ty + i*4]);
  } else if (bid < 192) {          // W_pred (256x60) -> WpT (64x256, zero-padded)
    int idx = (bid - 128) * 256 + tid;
    int c = idx >> 8, k = idx & 255;
    a.wpt[idx] = __float2bfloat16(c < 60 ? a.W_pred[k * 60 + c] : 0.f);
  } else if (bid < 200) {          // zero stats (2048 floats)
    a.ws[(bid - 192) * 256 + tid] = 0.f;
  } else {                         // zero Sacc: 262144 floats, float4 (256 blocks)
    int idx = (bid - 200) * 1024 + tid * 4;
    *reinterpret_cast<float4*>(a.ws + OFF_SACC + idx) = (float4){0.f, 0.f, 0.f, 0.f};
  }
}

// ---- XR = x @ W1_top + b1 ; XS = x @ W1_bot. grid 64 (32 rows/block) ----
__global__ __launch_bounds__(256) void k_xrs(
    const float* __restrict__ centers,
    const float* __restrict__ W_traj,
    const float* __restrict__ b_traj,
    const __hip_bfloat16* __restrict__ W1T,   // 256 x 512 n-major
    const float* __restrict__ b1,
    __hip_bfloat16* __restrict__ xrs) {       // XR ++ XS
  __shared__ alignas(16) __hip_bfloat16 xls[32][264];
  const int tid = threadIdx.x;
  const int w = tid >> 6, lane = tid & 63;
  const int m16 = lane & 15, quad = lane >> 4;
  const int ko = quad * 8;
  const int half = blockIdx.x >> 5;           // 0 = XR (+b1), 1 = XS
  const int row0 = (blockIdx.x & 31) * 32;
  const int colw = w * 64;
  __hip_bfloat16* dst = xrs + (size_t)half * 262144;

  #pragma unroll 4
  for (int r = 0; r < 32; ++r)
    xls[r][tid] = __float2bfloat16(xembed(centers, W_traj, b_traj, row0 + r, tid));
  __syncthreads();

  f32x4 acc[2][4];
  #pragma unroll
  for (int jt = 0; jt < 4; ++jt) {
    float bv = half ? 0.f : b1[colw + jt*16 + m16];
    #pragma unroll
    for (int mt = 0; mt < 2; ++mt) acc[mt][jt] = (f32x4){bv, bv, bv, bv};
  }
  #pragma unroll
  for (int ks = 0; ks < 8; ++ks) {
    short8 af[2], bf[4];
    #pragma unroll
    for (int mt = 0; mt < 2; ++mt)
      af[mt] = *reinterpret_cast<const short8*>(&xls[mt*16 + m16][ks*32 + ko]);
    #pragma unroll
    for (int jt = 0; jt < 4; ++jt)
      bf[jt] = *reinterpret_cast<const short8*>(
          W1T + (size_t)(colw + jt*16 + m16)*512 + half*256 + ks*32 + ko);
    #pragma unroll
    for (int mt = 0; mt < 2; ++mt)
      #pragma unroll
      for (int jt = 0; jt < 4; ++jt)
        acc[mt][jt] = __builtin_amdgcn_mfma_f32_16x16x32_bf16(af[mt], bf[jt],
                                                              acc[mt][jt], 0, 0, 0);
  }
  #pragma unroll
  for (int mt = 0; mt < 2; ++mt)
    #pragma unroll
    for (int jt = 0; jt < 4; ++jt)
      #pragma unroll
      for (int r = 0; r < 4; ++r)
        dst[(size_t)(row0 + mt*16 + quad*4 + r)*256 + colw + jt*16 + m16] =
            __float2bfloat16(acc[mt][jt][r]);
}

// ================= edge MLP: factored layer-1; e2 store + receiver-sum atomics ==
__global__ __launch_bounds__(256, 2) void k_mlp6(
    const __hip_bfloat16* __restrict__ xrs,   // XR ++ XS
    const __hip_bfloat16* __restrict__ W2T,   // 256 x 256, n-major
    const float* __restrict__ b2,
    __hip_bfloat16* __restrict__ outp,        // e2
    float* __restrict__ stats,
    float* __restrict__ Sacc) {
  __shared__ alignas(16) char reg1[33792];    // [0,32768): XS[b]; then 2 XR rows
  __shared__ alignas(16) __hip_bfloat16 h1s[64][264];
  __shared__ float sst[2][256];               // block stats
  __shared__ float ssr[2][256];               // block receiver sums (n0, n0+1)
  __shared__ int sd64[64];
  __shared__ int rcf[64];
  const int tid = threadIdx.x;
  const int w = tid >> 6, lane = tid & 63;
  const int m16 = lane & 15, quad = lane >> 4;
  const int ko = quad * 8;
  const int blk = blockIdx.x;                 // 1008
  const int bb = blk / 63, lb = blk - bb*63;
  const int row0 = blk * 64;
  const int n0 = (lb * 64) / 63;              // receivers are n0, n0+1
  const int colw = w * 64;

  // ---- stage XS[b] + 2 XR rows; index tables; zero LDS accumulators ----
  const char* xsb = (const char*)(xrs + 262144 + (size_t)bb*64*256);
  #pragma unroll
  for (int i = 0; i < 8; ++i) {
    int seg = w*8 + i;
    gl2lds16(xsb + seg*1024 + lane*16, reg1 + seg*1024);
  }
  if (w == 0)
    gl2lds16((const char*)(xrs + (size_t)(bb*64 + n0)*256) + lane*16, reg1 + 32768);
  if (tid < 64) {
    int e = lb*64 + tid;
    int rc = e / 63; int jj = e - rc*63;
    sd64[tid] = jj + (jj >= rc ? 1 : 0);
    rcf[tid]  = rc - n0;                      // 0 or 1
  }
  sst[0][tid] = 0.f; sst[1][tid] = 0.f;
  ssr[0][tid] = 0.f; ssr[1][tid] = 0.f;
  __syncthreads();

  // ---- h1 = elu(XR[rc] + XS[sd]) -> h1s ----
  {
    const int ty = tid >> 7;
    const int c2 = (tid & 127) * 2;
    #pragma unroll 4
    for (int r2 = 0; r2 < 32; ++r2) {
      int r = ty*32 + r2;
      __hip_bfloat162 xa = *reinterpret_cast<const __hip_bfloat162*>(
          reg1 + 32768 + rcf[r]*512 + c2*2);
      __hip_bfloat162 xs2 = *reinterpret_cast<const __hip_bfloat162*>(
          reg1 + sd64[r]*512 + c2*2);
      __hip_bfloat162 o;
      o.x = __float2bfloat16(eluf(__bfloat162float(xa.x) + __bfloat162float(xs2.x)));
      o.y = __float2bfloat16(eluf(__bfloat162float(xa.y) + __bfloat162float(xs2.y)));
      *reinterpret_cast<__hip_bfloat162*>(&h1s[r][c2]) = o;
    }
  }
  __syncthreads();

  // ---- layer 2: 64x256 @ 256x256, B direct from global (L2-hot 128 KB) ----
  f32x4 acc2[4][4];
  #pragma unroll
  for (int jt = 0; jt < 4; ++jt) {
    float bv = b2[colw + jt*16 + m16];
    #pragma unroll
    for (int mt = 0; mt < 4; ++mt) acc2[mt][jt] = (f32x4){bv, bv, bv, bv};
  }
  #pragma unroll
  for (int kt = 0; kt < 4; ++kt) {
    #pragma unroll
    for (int ks = 0; ks < 2; ++ks) {
      const int k0 = kt*64 + ks*32 + ko;
      short8 af[4], bf[4];
      #pragma unroll
      for (int jt = 0; jt < 4; ++jt)
        bf[jt] = *reinterpret_cast<const short8*>(
            W2T + (size_t)(colw + jt*16 + m16)*256 + k0);
      #pragma unroll
      for (int mt = 0; mt < 4; ++mt)
        af[mt] = *(const short8*)((const char*)h1s +
                     (size_t)(mt*16 + m16)*528 + k0*2);
      #pragma unroll
      for (int mt = 0; mt < 4; ++mt)
        #pragma unroll
        for (int jt = 0; jt < 4; ++jt)
          acc2[mt][jt] = __builtin_amdgcn_mfma_f32_16x16x32_bf16(af[mt], bf[jt],
                                                                 acc2[mt][jt], 0, 0, 0);
    }
  }
  __syncthreads();   // all h1 reads done before h1s is overwritten with h2

  // ---- ELU(h2) -> h1s; stats + receiver sums from registers ----
  #pragma unroll
  for (int jt = 0; jt < 4; ++jt) {
    float ps = 0.f, pq = 0.f, pr0 = 0.f, pr1 = 0.f;
    #pragma unroll
    for (int mt = 0; mt < 4; ++mt)
      #pragma unroll
      for (int r = 0; r < 4; ++r) {
        float hv = eluf(acc2[mt][jt][r]);
        h1s[mt*16 + quad*4 + r][colw + jt*16 + m16] = __float2bfloat16(hv);
        ps += hv; pq += hv * hv;
        if (rcf[mt*16 + quad*4 + r] == 0) pr0 += hv; else pr1 += hv;
      }
    int c = colw + jt*16 + m16;
    atomicAdd(&sst[0][c], ps);
    atomicAdd(&sst[1][c], pq);
    atomicAdd(&ssr[0][c], pr0);
    atomicAdd(&ssr[1][c], pr1);
  }
  __syncthreads();

  // ---- global: stats + 2 receiver-sum atomics per column + e2 store ----
  atomicAdd(&stats[tid], sst[0][tid]);
  atomicAdd(&stats[256 + tid], sst[1][tid]);
  atomicAdd(&Sacc[(size_t)(bb*64 + n0)*256 + tid], ssr[0][tid]);
  atomicAdd(&Sacc[(size_t)(bb*64 + n0 + 1)*256 + tid], ssr[1][tid]);
  #pragma unroll
  for (int i = 0; i < 8; ++i) {
    int u = i*256 + tid;
    int r = u >> 5, c = (u & 31) * 8;
    *reinterpret_cast<uint4*>(outp + (size_t)(row0 + r)*HH + c) =
        *reinterpret_cast<const uint4*>(&h1s[r][c]);
  }
}

// ---- agg: T (sender) sums from e2, S from Sacc; one block per (b,n) ----
__global__ __launch_bounds__(1024) void k_agg3(const __hip_bfloat16* __restrict__ e2,
                                               const float* __restrict__ Sacc,
                                               const float* __restrict__ st,
                                               const float* __restrict__ gam,
                                               const float* __restrict__ bet,
                                               __hip_bfloat16* __restrict__ nodes) {
  __shared__ float red[32][256];
  const int bn = blockIdx.x;
  const int b = bn >> 6, n = bn & 63;
  const int tid = threadIdx.x;
  const int c8 = (tid & 31) * 8;
  const int rg = tid >> 5;        // 0..31
  const __hip_bfloat16* base = e2 + (size_t)b * EE * HH;
  float s[8] = {0.f,0.f,0.f,0.f,0.f,0.f,0.f,0.f};
  for (int j = rg; j < 63; j += 32) {
    int i = j + (j >= n ? 1 : 0);
    int e = i*63 + n - (n > i ? 1 : 0);
    union { uint4 u; __hip_bfloat16 h[8]; } v;
    v.u = *reinterpret_cast<const uint4*>(base + (size_t)e*HH + c8);
    #pragma unroll
    for (int jj = 0; jj < 8; ++jj) s[jj] += __bfloat162float(v.h[jj]);
  }
  #pragma unroll
  for (int jj = 0; jj < 8; jj += 4)
    *reinterpret_cast<float4*>(&red[rg][c8 + jj]) =
        (float4){s[jj], s[jj+1], s[jj+2], s[jj+3]};
  __syncthreads();
  if (tid < 256) {
    float T = 0.f;
    #pragma unroll
    for (int r = 0; r < 32; ++r) T += red[r][tid];
    float S = Sacc[(size_t)bn*256 + tid];
    const float inv = 1.f / (float)EROWS;
    float mean = st[tid] * inv;
    float var  = fmaxf(st[256 + tid] * inv - mean*mean, 0.f);
    float a = gam[tid] * rsqrtf(var + 1e-5f);
    float c0 = bet[tid] - mean * a;
    nodes[(size_t)bn*512 + tid]       = __float2bfloat16(a * S * (1.f/63.f) + c0);
    nodes[(size_t)bn*512 + 256 + tid] = __float2bfloat16(a * T * (1.f/63.f) + c0);
  }
}

// ================= node MLP (round-5 proven structure) =========================
__global__ __launch_bounds__(256, 2) void k_mlp3n(
    const __hip_bfloat16* __restrict__ A,
    const __hip_bfloat16* __restrict__ W1T,   // 256 x 512, n-major
    const float* __restrict__ b1,
    const __hip_bfloat16* __restrict__ W2T,   // 256 x 256, n-major
    const float* __restrict__ b2,
    __hip_bfloat16* __restrict__ outp,
    float* __restrict__ stats) {
  __shared__ alignas(16) __hip_bfloat16 Wt[256 * 64];
  __shared__ alignas(16) __hip_bfloat16 At[16 * 64];
  __shared__ alignas(16) __hip_bfloat16 h1s[16][264];
  const int tid = threadIdx.x;
  const int w = tid >> 6, lane = tid & 63;
  const int m16 = lane & 15, quad = lane >> 4;
  const int ko = quad * 8;
  const int row0 = blockIdx.x * 16;
  const int colw = w * 64;
  const int csub = lane >> 3, jl = lane & 7;
  const int jsrc = jl ^ csub;
  const int swz0 = ((quad)     ^ (m16 & 7)) * 16;
  const int swz1 = ((quad + 4) ^ (m16 & 7)) * 16;

  const __hip_bfloat16 *ar0 = nullptr, *ar1 = nullptr;
  if (w < 2) {
    int r = w * 8 + csub;
    ar0 = A + (size_t)(row0 + r) * 512;
    ar1 = ar0 + 256;
  }

  f32x4 acc[4];
  #pragma unroll
  for (int jt = 0; jt < 4; ++jt) {
    float bv = b1[colw + jt*16 + m16];
    acc[jt] = (f32x4){bv, bv, bv, bv};
  }
  for (int kt = 0; kt < 8; ++kt) {
    const int k0 = kt * 64;
    #pragma unroll
    for (int i = 0; i < 8; ++i) {
      const __hip_bfloat16* gp = W1T + (size_t)(colw + i*8 + csub) * 512 + k0 + jsrc*8;
      gl2lds16(gp, (char*)Wt + w*8192 + i*1024);
    }
    if (w < 2) {
      const __hip_bfloat16* gp = (k0 < 256 ? ar0 + k0 : ar1 + (k0 - 256)) + jsrc*8;
      gl2lds16(gp, (char*)At + w*1024);
    }
    __syncthreads();
    #pragma unroll
    for (int ks = 0; ks < 2; ++ks) {
      const int sw = ks ? swz1 : swz0;
      short8 af = *(const short8*)((const char*)At + m16*128 + sw);
      short8 bf[4];
      #pragma unroll
      for (int jt = 0; jt < 4; ++jt)
        bf[jt] = *(const short8*)((const char*)Wt + (colw + jt*16 + m16)*128 + sw);
      #pragma unroll
      for (int jt = 0; jt < 4; ++jt)
        acc[jt] = __builtin_amdgcn_mfma_f32_16x16x32_bf16(af, bf[jt], acc[jt], 0, 0, 0);
    }
    __syncthreads();
  }
  #pragma unroll
  for (int jt = 0; jt < 4; ++jt)
    #pragma unroll
    for (int r = 0; r < 4; ++r)
      h1s[quad*4 + r][colw + jt*16 + m16] = __float2bfloat16(eluf(acc[jt][r]));
  __syncthreads();

  f32x4 acc2[4];
  #pragma unroll
  for (int jt = 0; jt < 4; ++jt) {
    float bv = b2[colw + jt*16 + m16];
    acc2[jt] = (f32x4){bv, bv, bv, bv};
  }
  #pragma unroll
  for (int kt = 0; kt < 4; ++kt) {
    #pragma unroll
    for (int ks = 0; ks < 2; ++ks) {
      const int k0 = kt*64 + ks*32 + ko;
      short8 af = *(const short8*)((const char*)h1s + (size_t)m16*528 + k0*2);
      short8 bf[4];
      #pragma unroll
      for (int jt = 0; jt < 4; ++jt)
        bf[jt] = *reinterpret_cast<const short8*>(
            W2T + (size_t)(colw + jt*16 + m16)*256 + k0);
      #pragma unroll
      for (int jt = 0; jt < 4; ++jt)
        acc2[jt] = __builtin_amdgcn_mfma_f32_16x16x32_bf16(af, bf[jt], acc2[jt], 0, 0, 0);
    }
  }
  __syncthreads();
  #pragma unroll
  for (int jt = 0; jt < 4; ++jt)
    #pragma unroll
    for (int r = 0; r < 4; ++r)
      h1s[quad*4 + r][colw + jt*16 + m16] = __float2bfloat16(eluf(acc2[jt][r]));
  __syncthreads();

  {
    float s = 0.f, q = 0.f;
    #pragma unroll 8
    for (int r = 0; r < 16; ++r) {
      float v = __bfloat162float(h1s[r][tid]);
      s += v; q += v * v;
    }
    atomicAdd(&stats[tid], s);
    atomicAdd(&stats[256 + tid], q);
  }
  #pragma unroll
  for (int i = 0; i < 2; ++i) {
    int u = i*256 + tid;
    int r = u >> 5, c = (u & 31) * 8;
    *reinterpret_cast<uint4*>(outp + (size_t)(row0 + r)*HH + c) =
        *reinterpret_cast<const uint4*>(&h1s[r][c]);
  }
}

// ---- head: 16-row blocks (grid 64), x recomputed in-kernel, BN(m2) inline ----
__global__ __launch_bounds__(256) void k_head2(
    const float* __restrict__ centers,
    const float* __restrict__ W_traj,
    const float* __restrict__ b_traj,
    const __hip_bfloat16* __restrict__ m2,
    const float* __restrict__ stM,
    const float* __restrict__ gam,
    const float* __restrict__ bet,
    const __hip_bfloat16* __restrict__ WfT,
    const float* __restrict__ bfv,
    const __hip_bfloat16* __restrict__ WpT,
    const float* __restrict__ bp,
    float* __restrict__ out) {
  __shared__ alignas(16) __hip_bfloat16 xs[16][264];
  __shared__ alignas(16) __hip_bfloat16 hs[16][264];
  __shared__ float rl[16][64];
  __shared__ float bnA[256], bnC[256];
  const int tid = threadIdx.x;
  const int w = tid >> 6, lane = tid & 63;
  const int m16 = lane & 15, quad = lane >> 4;
  const int ko = quad * 8;
  const int row0 = blockIdx.x * 16;
  const int colw = w * 64;

  {
    const float inv = 1.f / (float)NROWS;
    float mean = stM[tid] * inv;
    float var  = fmaxf(stM[256 + tid] * inv - mean*mean, 0.f);
    float am = gam[tid] * rsqrtf(var + 1e-5f);
    bnA[tid] = am;
    bnC[tid] = bet[tid] - mean * am;
  }
  #pragma unroll
  for (int r = 0; r < 16; ++r)
    xs[r][tid] = __float2bfloat16(xembed(centers, W_traj, b_traj, row0 + r, tid));
  __syncthreads();

  f32x4 acc[4];
  #pragma unroll
  for (int jt = 0; jt < 4; ++jt) {
    float bv = bfv[colw + jt*16 + m16];
    acc[jt] = (f32x4){bv, bv, bv, bv};
  }
  #pragma unroll
  for (int ks = 0; ks < 16; ++ks) {
    short8 af;
    if (ks < 8) {
      af = *reinterpret_cast<const short8*>(&xs[m16][ks*32 + ko]);
    } else {
      int k0 = (ks - 8)*32 + ko;
      union { uint4 u; __hip_bfloat16 h[8]; } v;
      v.u = *reinterpret_cast<const uint4*>(m2 + (size_t)(row0 + m16)*256 + k0);
      union { short8 s8; __hip_bfloat16 h[8]; } o;
      #pragma unroll
      for (int j = 0; j < 8; ++j)
        o.h[j] = __float2bfloat16(bnA[k0+j] * __bfloat162float(v.h[j]) + bnC[k0+j]);
      af = o.s8;
    }
    short8 bf[4];
    #pragma unroll
    for (int jt = 0; jt < 4; ++jt)
      bf[jt] = *reinterpret_cast<const short8*>(
          WfT + (size_t)(colw + jt*16 + m16)*512 + ks*32 + ko);
    #pragma unroll
    for (int jt = 0; jt < 4; ++jt)
      acc[jt] = __builtin_amdgcn_mfma_f32_16x16x32_bf16(af, bf[jt], acc[jt], 0, 0, 0);
  }
  #pragma unroll
  for (int jt = 0; jt < 4; ++jt)
    #pragma unroll
    for (int r = 0; r < 4; ++r)
      hs[quad*4 + r][colw + jt*16 + m16] = __float2bfloat16(acc[jt][r]);
  __syncthreads();

  if (w == 0) {
    f32x4 acc2[4];
    #pragma unroll
    for (int jt = 0; jt < 4; ++jt) {
      int c = jt*16 + m16;
      float bv = (c < 60) ? bp[c] : 0.f;
      acc2[jt] = (f32x4){bv, bv, bv, bv};
    }
    #pragma unroll
    for (int ks = 0; ks < 8; ++ks) {
      short8 af = *reinterpret_cast<const short8*>(&hs[m16][ks*32 + ko]);
      short8 bf[4];
      #pragma unroll
      for (int jt = 0; jt < 4; ++jt)
        bf[jt] = *reinterpret_cast<const short8*>(
            WpT + (size_t)(jt*16 + m16)*256 + ks*32 + ko);
      #pragma unroll
      for (int jt = 0; jt < 4; ++jt)
        acc2[jt] = __builtin_amdgcn_mfma_f32_16x16x32_bf16(af, bf[jt], acc2[jt], 0, 0, 0);
    }
    #pragma unroll
    for (int jt = 0; jt < 4; ++jt) {
      int c = jt*16 + m16;
      #pragma unroll
      for (int r = 0; r < 4; ++r) {
        int lr = quad*4 + r;
        rl[lr][c] = acc2[jt][r];
        if (c < 60) out[(size_t)(row0 + lr)*60 + c] = acc2[jt][r];
      }
    }
  }
  __syncthreads();

  if (tid < 32) {
    int lr = tid >> 1, xy = tid & 1;
    int grow = row0 + lr;
    float run = centers[(size_t)(grow*PREVN + 5)*2 + xy];
    #pragma unroll
    for (int p = 0; p < PREDN; ++p) {
      run += rl[lr][2*p + xy];
      out[61440 + (size_t)grow*60 + 2*p + xy] = run;
    }
  }
}

extern "C" void kernel_launch(void* const* d_in, const int* in_sizes, int n_in,
                              void* d_out, int out_size, void* d_ws, size_t ws_size,
                              hipStream_t stream) {
  const float* centers = (const float*)d_in[0];
  float* ws = (float*)d_ws;
  __hip_bfloat16* wb = (__hip_bfloat16*)(ws + F32_END);
  __hip_bfloat16* xrs = (__hip_bfloat16*)(ws + OFF_XRS);

  const float* W_traj = (const float*)d_in[3];
  const float* b_traj = (const float*)d_in[4];
  const float* n2e_b1 = (const float*)d_in[6];
  const float* n2e_b2 = (const float*)d_in[8];
  const float* n2e_g  = (const float*)d_in[9];
  const float* n2e_be = (const float*)d_in[10];
  const float* e2n_b1 = (const float*)d_in[12];
  const float* e2n_b2 = (const float*)d_in[14];
  const float* e2n_g  = (const float*)d_in[15];
  const float* e2n_be = (const float*)d_in[16];
  const float* b_fuse = (const float*)d_in[18];
  const float* b_pred = (const float*)d_in[20];

  PrepArgs pa;
  pa.n2e_W1 = (const float*)d_in[5];  pa.n2e_W2 = (const float*)d_in[7];
  pa.e2n_W1 = (const float*)d_in[11]; pa.e2n_W2 = (const float*)d_in[13];
  pa.W_fuse = (const float*)d_in[17]; pa.W_pred = (const float*)d_in[19];
  pa.ws = ws;
  pa.w1te = wb + BO_W1TE; pa.w2te = wb + BO_W2TE;
  pa.w1tn = wb + BO_W1TN; pa.w2tn = wb + BO_W2TN;
  pa.wft = wb + BO_WFT;   pa.wpt = wb + BO_WPT;

  k_prep<<<456, 256, 0, stream>>>(pa);
  k_xrs<<<64, 256, 0, stream>>>(centers, W_traj, b_traj, wb + BO_W1TE, n2e_b1, xrs);
  k_mlp6<<<EROWS/64, 256, 0, stream>>>(xrs, wb + BO_W2TE, n2e_b2, wb + BO_E2,
                                       ws + OFF_STATS_E, ws + OFF_SACC);
  k_agg3<<<NROWS, 1024, 0, stream>>>(wb + BO_E2, ws + OFF_SACC, ws + OFF_STATS_E,
                                     n2e_g, n2e_be, wb + BO_NODES);
  k_mlp3n<<<NROWS/16, 256, 0, stream>>>(wb + BO_NODES, wb + BO_W1TN, e2n_b1,
                                        wb + BO_W2TN, e2n_b2,
                                        wb + BO_M2, ws + OFF_STATS_M);
  k_head2<<<NROWS/16, 256, 0, stream>>>(centers, W_traj, b_traj, wb + BO_M2,
                                        ws + OFF_STATS_M, e2n_g, e2n_be,
                                        wb + BO_WFT, b_fuse, wb + BO_WPT, b_pred,
                                        (float*)d_out);
}

// Round 15
// 201.711 us; speedup vs baseline: 1.2099x; 1.0680x over previous
//
#include <hip/hip_runtime.h>
#include <hip/hip_bf16.h>

#define BB 16
#define NN 64
#define PREVN 6
#define PREDN 30
#define HH 256
#define EE 4032              // NN*(NN-1)
#define EROWS (BB*EE)        // 64512
#define NROWS (BB*NN)        // 1024

typedef short short8 __attribute__((ext_vector_type(8)));
typedef float f32x4 __attribute__((ext_vector_type(4)));

// ---- f32 workspace layout (float element offsets) ----
enum : int {
  OFF_STATS_E = 0,       // 1024: [0:256]=sum [256:512]=sumsq
  OFF_STATS_M = 1024,    // 1024
  OFF_XRS     = 2048,    // 262144 f32 slots = 524288 bf16: XR ++ XS
  F32_END     = 264192
};
// ---- bf16 area (element offsets within wb = (bf16*)(ws + F32_END)) ----
enum : size_t {
  BO_W1TE  = 0,          // 256*512 (n2e W1^T)
  BO_W2TE  = 131072,     // 256*256
  BO_W1TN  = 196608,     // 256*512 (e2n W1^T)
  BO_W2TN  = 327680,     // 256*256
  BO_WFT   = 393216,     // 256*512 (W_fuse^T)
  BO_WPT   = 524288,     // 64*256  (W_pred^T, zero-padded cols 60..63)
  BO_XG    = 540672,     // 1024*256 raw x (bf16)
  BO_NODES = 802816,     // 1024*512
  BO_H1G   = 1327104,    // 1024*256 node-MLP h1
  BO_M2    = 1589248,    // 1024*256
  BO_FG    = 1851392,    // 1024*256 fused
  BO_E2    = 2113536     // 64512*256
};

// fast ELU: exp(x)-1 via v_exp_f32
__device__ __forceinline__ float eluf(float v) { return v > 0.f ? v : __expf(v) - 1.f; }

// async global -> LDS, 16 B per lane
__device__ __forceinline__ void gl2lds16(const void* g, void* l) {
  __builtin_amdgcn_global_load_lds(
      (const __attribute__((address_space(1))) void*)g,
      (__attribute__((address_space(3))) void*)l, 16, 0, 0);
}

// compute one x-embed element: row rr (global), col
__device__ __forceinline__ float xembed(const float* __restrict__ centers,
                                        const float* __restrict__ Wt,
                                        const float* __restrict__ bt,
                                        int rr, int col) {
  const float* c = centers + rr * 12;
  float acc = bt[col];
  #pragma unroll
  for (int t = 0; t < 5; ++t) {
    float dx = c[(t+1)*2 + 0] - c[t*2 + 0];
    float dy = c[(t+1)*2 + 1] - c[t*2 + 1];
    acc += dx * Wt[(2 + 2*t)*HH + col] + dy * Wt[(3 + 2*t)*HH + col];
  }
  return acc;
}

// ================= prep: transposes + wpt + zero stats =========================
struct PrepArgs {
  const float *n2e_W1, *n2e_W2, *e2n_W1, *e2n_W2, *W_fuse, *W_pred;
  float* ws;
  __hip_bfloat16 *w1te, *w2te, *w1tn, *w2tn, *wft, *wpt;
};

__global__ __launch_bounds__(256) void k_prep(PrepArgs a) {
  __shared__ float t[64][65];
  const int bid = blockIdx.x, tid = threadIdx.x;
  if (bid < 128) {
    const float* W; __hip_bfloat16* WT; int K, lb;
    if (bid < 32)      { W = a.n2e_W1; WT = a.w1te; K = 512; lb = bid; }
    else if (bid < 48) { W = a.n2e_W2; WT = a.w2te; K = 256; lb = bid - 32; }
    else if (bid < 80) { W = a.e2n_W1; WT = a.w1tn; K = 512; lb = bid - 48; }
    else if (bid < 96) { W = a.e2n_W2; WT = a.w2tn; K = 256; lb = bid - 80; }
    else               { W = a.W_fuse; WT = a.wft;  K = 512; lb = bid - 96; }
    int KB = K / 64;
    int k0 = (lb % KB) * 64, n0 = (lb / KB) * 64;
    int tx = tid & 63, ty = tid >> 6;
    #pragma unroll
    for (int i = 0; i < 16; ++i)
      t[ty + i*4][tx] = W[(size_t)(k0 + ty + i*4) * 256 + n0 + tx];
    __syncthreads();
    #pragma unroll
    for (int i = 0; i < 16; ++i)
      WT[(size_t)(n0 + ty + i*4) * K + k0 + tx] = __float2bfloat16(t[tx][ty + i*4]);
  } else if (bid < 192) {
    int idx = (bid - 128) * 256 + tid;
    int c = idx >> 8, k = idx & 255;
    a.wpt[idx] = __float2bfloat16(c < 60 ? a.W_pred[k * 60 + c] : 0.f);
  } else {
    a.ws[(bid - 192) * 256 + tid] = 0.f;
  }
}

// ---- XR/XS = x @ W1_{top,bot}; also emits raw x (xg). grid 64 (32 rows/blk) ----
__global__ __launch_bounds__(256) void k_xrs(
    const float* __restrict__ centers,
    const float* __restrict__ W_traj,
    const float* __restrict__ b_traj,
    const __hip_bfloat16* __restrict__ W1T,   // 256 x 512 n-major
    const float* __restrict__ b1,
    __hip_bfloat16* __restrict__ xrs,         // XR ++ XS
    __hip_bfloat16* __restrict__ xg) {        // raw x 1024x256
  __shared__ alignas(16) __hip_bfloat16 xls[32][264];
  const int tid = threadIdx.x;
  const int w = tid >> 6, lane = tid & 63;
  const int m16 = lane & 15, quad = lane >> 4;
  const int ko = quad * 8;
  const int half = blockIdx.x >> 5;           // 0 = XR (+b1), 1 = XS
  const int row0 = (blockIdx.x & 31) * 32;
  const int colw = w * 64;
  __hip_bfloat16* dst = xrs + (size_t)half * 262144;

  #pragma unroll 4
  for (int r = 0; r < 32; ++r)
    xls[r][tid] = __float2bfloat16(xembed(centers, W_traj, b_traj, row0 + r, tid));
  __syncthreads();

  if (half == 0) {   // emit raw x for the head
    #pragma unroll
    for (int i = 0; i < 4; ++i) {
      int u = i*256 + tid;
      int r = u >> 5, c = (u & 31) * 8;
      *reinterpret_cast<uint4*>(xg + (size_t)(row0 + r)*256 + c) =
          *reinterpret_cast<const uint4*>(&xls[r][c]);
    }
  }

  f32x4 acc[2][4];
  #pragma unroll
  for (int jt = 0; jt < 4; ++jt) {
    float bv = half ? 0.f : b1[colw + jt*16 + m16];
    #pragma unroll
    for (int mt = 0; mt < 2; ++mt) acc[mt][jt] = (f32x4){bv, bv, bv, bv};
  }
  #pragma unroll
  for (int ks = 0; ks < 8; ++ks) {
    short8 af[2], bf[4];
    #pragma unroll
    for (int mt = 0; mt < 2; ++mt)
      af[mt] = *reinterpret_cast<const short8*>(&xls[mt*16 + m16][ks*32 + ko]);
    #pragma unroll
    for (int jt = 0; jt < 4; ++jt)
      bf[jt] = *reinterpret_cast<const short8*>(
          W1T + (size_t)(colw + jt*16 + m16)*512 + half*256 + ks*32 + ko);
    #pragma unroll
    for (int mt = 0; mt < 2; ++mt)
      #pragma unroll
      for (int jt = 0; jt < 4; ++jt)
        acc[mt][jt] = __builtin_amdgcn_mfma_f32_16x16x32_bf16(af[mt], bf[jt],
                                                              acc[mt][jt], 0, 0, 0);
  }
  #pragma unroll
  for (int mt = 0; mt < 2; ++mt)
    #pragma unroll
    for (int jt = 0; jt < 4; ++jt)
      #pragma unroll
      for (int r = 0; r < 4; ++r)
        dst[(size_t)(row0 + mt*16 + quad*4 + r)*256 + colw + jt*16 + m16] =
            __float2bfloat16(acc[mt][jt][r]);
}

// ================= edge MLP (round-12 proven): factored L1 + reg stats =========
__global__ __launch_bounds__(256, 2) void k_mlp6(
    const __hip_bfloat16* __restrict__ xrs,   // XR ++ XS
    const __hip_bfloat16* __restrict__ W2T,   // 256 x 256, n-major
    const float* __restrict__ b2,
    __hip_bfloat16* __restrict__ outp,        // e2
    float* __restrict__ stats) {
  __shared__ alignas(16) char reg1[33792];
  __shared__ alignas(16) __hip_bfloat16 h1s[64][264];
  __shared__ float sst[2][256];
  const int tid = threadIdx.x;
  const int w = tid >> 6, lane = tid & 63;
  const int m16 = lane & 15, quad = lane >> 4;
  const int ko = quad * 8;
  const int blk = blockIdx.x;                 // 1008
  const int bb = blk / 63, lb = blk - bb*63;
  const int row0 = blk * 64;
  const int n0 = (lb * 64) / 63;
  const int colw = w * 64;

  const char* xsb = (const char*)(xrs + 262144 + (size_t)bb*64*256);
  #pragma unroll
  for (int i = 0; i < 8; ++i) {
    int seg = w*8 + i;
    gl2lds16(xsb + seg*1024 + lane*16, reg1 + seg*1024);
  }
  if (w == 0)
    gl2lds16((const char*)(xrs + (size_t)(bb*64 + n0)*256) + lane*16, reg1 + 32768);
  sst[0][tid] = 0.f;
  sst[1][tid] = 0.f;
  __syncthreads();

  {
    const int ty = tid >> 7;
    const int c2 = (tid & 127) * 2;
    #pragma unroll 4
    for (int r2 = 0; r2 < 32; ++r2) {
      int r = ty*32 + r2;
      int e = lb*64 + r;
      int rc = e / 63; int jj = e - rc*63;
      int sd = jj + (jj >= rc ? 1 : 0);
      __hip_bfloat162 xa = *reinterpret_cast<const __hip_bfloat162*>(
          reg1 + 32768 + (rc - n0)*512 + c2*2);
      __hip_bfloat162 xs2 = *reinterpret_cast<const __hip_bfloat162*>(
          reg1 + sd*512 + c2*2);
      __hip_bfloat162 o;
      o.x = __float2bfloat16(eluf(__bfloat162float(xa.x) + __bfloat162float(xs2.x)));
      o.y = __float2bfloat16(eluf(__bfloat162float(xa.y) + __bfloat162float(xs2.y)));
      *reinterpret_cast<__hip_bfloat162*>(&h1s[r][c2]) = o;
    }
  }
  __syncthreads();

  f32x4 acc2[4][4];
  #pragma unroll
  for (int jt = 0; jt < 4; ++jt) {
    float bv = b2[colw + jt*16 + m16];
    #pragma unroll
    for (int mt = 0; mt < 4; ++mt) acc2[mt][jt] = (f32x4){bv, bv, bv, bv};
  }
  #pragma unroll
  for (int kt = 0; kt < 4; ++kt) {
    #pragma unroll
    for (int ks = 0; ks < 2; ++ks) {
      const int k0 = kt*64 + ks*32 + ko;
      short8 af[4], bf[4];
      #pragma unroll
      for (int jt = 0; jt < 4; ++jt)
        bf[jt] = *reinterpret_cast<const short8*>(
            W2T + (size_t)(colw + jt*16 + m16)*256 + k0);
      #pragma unroll
      for (int mt = 0; mt < 4; ++mt)
        af[mt] = *(const short8*)((const char*)h1s +
                     (size_t)(mt*16 + m16)*528 + k0*2);
      #pragma unroll
      for (int mt = 0; mt < 4; ++mt)
        #pragma unroll
        for (int jt = 0; jt < 4; ++jt)
          acc2[mt][jt] = __builtin_amdgcn_mfma_f32_16x16x32_bf16(af[mt], bf[jt],
                                                                 acc2[mt][jt], 0, 0, 0);
    }
  }
  __syncthreads();

  #pragma unroll
  for (int jt = 0; jt < 4; ++jt) {
    float ps = 0.f, pq = 0.f;
    #pragma unroll
    for (int mt = 0; mt < 4; ++mt)
      #pragma unroll
      for (int r = 0; r < 4; ++r) {
        float hv = eluf(acc2[mt][jt][r]);
        h1s[mt*16 + quad*4 + r][colw + jt*16 + m16] = __float2bfloat16(hv);
        ps += hv; pq += hv * hv;
      }
    atomicAdd(&sst[0][colw + jt*16 + m16], ps);
    atomicAdd(&sst[1][colw + jt*16 + m16], pq);
  }
  __syncthreads();

  atomicAdd(&stats[tid], sst[0][tid]);
  atomicAdd(&stats[256 + tid], sst[1][tid]);
  #pragma unroll
  for (int i = 0; i < 8; ++i) {
    int u = i*256 + tid;
    int r = u >> 5, c = (u & 31) * 8;
    *reinterpret_cast<uint4*>(outp + (size_t)(row0 + r)*HH + c) =
        *reinterpret_cast<const uint4*>(&h1s[r][c]);
  }
}

// ---- BN-fused edge->node aggregation (round-12 proven): grid 2048 x 1024 ----
__global__ __launch_bounds__(1024) void k_agg2(const __hip_bfloat16* __restrict__ e2,
                                               const float* __restrict__ st,
                                               const float* __restrict__ gam,
                                               const float* __restrict__ bet,
                                               __hip_bfloat16* __restrict__ nodes) {
  __shared__ float red[32][256];
  const int blk = blockIdx.x;
  const int bn = blk >> 1, half = blk & 1;
  const int b = bn >> 6, n = bn & 63;
  const int tid = threadIdx.x;
  const int c8 = (tid & 31) * 8;
  const int rg = tid >> 5;
  const __hip_bfloat16* base = e2 + (size_t)b * EE * HH;
  float s[8] = {0.f,0.f,0.f,0.f,0.f,0.f,0.f,0.f};
  for (int j = rg; j < 63; j += 32) {
    const __hip_bfloat16* rp;
    if (half == 0) {
      rp = base + (size_t)(n*63 + j)*HH;
    } else {
      int i = j + (j >= n ? 1 : 0);
      int e = i*63 + n - (n > i ? 1 : 0);
      rp = base + (size_t)e*HH;
    }
    union { uint4 u; __hip_bfloat16 h[8]; } v;
    v.u = *reinterpret_cast<const uint4*>(rp + c8);
    #pragma unroll
    for (int jj = 0; jj < 8; ++jj) s[jj] += __bfloat162float(v.h[jj]);
  }
  #pragma unroll
  for (int jj = 0; jj < 8; jj += 4)
    *reinterpret_cast<float4*>(&red[rg][c8 + jj]) =
        (float4){s[jj], s[jj+1], s[jj+2], s[jj+3]};
  __syncthreads();
  if (tid < 256) {
    float S = 0.f;
    #pragma unroll
    for (int r = 0; r < 32; ++r) S += red[r][tid];
    const float inv = 1.f / (float)EROWS;
    float mean = st[tid] * inv;
    float var  = fmaxf(st[256 + tid] * inv - mean*mean, 0.f);
    float a = gam[tid] * rsqrtf(var + 1e-5f);
    float c0 = bet[tid] - mean * a;
    nodes[(size_t)bn*512 + half*256 + tid] = __float2bfloat16(a * S * (1.f/63.f) + c0);
  }
}

// ================= node MLP layer 1: single-wave tiles, grid 256 ===============
__global__ __launch_bounds__(64) void k_n1(
    const __hip_bfloat16* __restrict__ nodes, // 1024 x 512
    const __hip_bfloat16* __restrict__ W1T,   // 256 x 512
    const float* __restrict__ b1,
    __hip_bfloat16* __restrict__ h1g) {       // 1024 x 256
  __shared__ alignas(16) __hip_bfloat16 hls[16][72];
  const int lane = threadIdx.x;
  const int m16 = lane & 15, quad = lane >> 4;
  const int ko = quad * 8;
  const int row0 = (blockIdx.x >> 2) * 16;
  const int j0 = (blockIdx.x & 3) * 64;

  f32x4 acc[4];
  #pragma unroll
  for (int jt = 0; jt < 4; ++jt) {
    float bv = b1[j0 + jt*16 + m16];
    acc[jt] = (f32x4){bv, bv, bv, bv};
  }
  #pragma unroll
  for (int ks = 0; ks < 16; ++ks) {
    short8 af = *reinterpret_cast<const short8*>(
        nodes + (size_t)(row0 + m16)*512 + ks*32 + ko);
    short8 bf[4];
    #pragma unroll
    for (int jt = 0; jt < 4; ++jt)
      bf[jt] = *reinterpret_cast<const short8*>(
          W1T + (size_t)(j0 + jt*16 + m16)*512 + ks*32 + ko);
    #pragma unroll
    for (int jt = 0; jt < 4; ++jt)
      acc[jt] = __builtin_amdgcn_mfma_f32_16x16x32_bf16(af, bf[jt], acc[jt], 0, 0, 0);
  }
  #pragma unroll
  for (int jt = 0; jt < 4; ++jt)
    #pragma unroll
    for (int r = 0; r < 4; ++r)
      hls[quad*4 + r][jt*16 + m16] = __float2bfloat16(eluf(acc[jt][r]));
  // single wave: LDS RAW handled by compiler waitcnt, no barrier needed
  #pragma unroll
  for (int i = 0; i < 2; ++i) {
    int u = i*64 + lane;
    int r = u >> 3, c = (u & 7) * 8;
    *reinterpret_cast<uint4*>(h1g + (size_t)(row0 + r)*256 + j0 + c) =
        *reinterpret_cast<const uint4*>(&hls[r][c]);
  }
}

// ================= node MLP layer 2 + stats: single-wave, grid 256 =============
__global__ __launch_bounds__(64) void k_n2(
    const __hip_bfloat16* __restrict__ h1g,   // 1024 x 256
    const __hip_bfloat16* __restrict__ W2T,   // 256 x 256
    const float* __restrict__ b2,
    __hip_bfloat16* __restrict__ m2,          // 1024 x 256
    float* __restrict__ stats) {
  __shared__ alignas(16) __hip_bfloat16 hls[16][72];
  __shared__ float sst[2][64];
  const int lane = threadIdx.x;
  const int m16 = lane & 15, quad = lane >> 4;
  const int ko = quad * 8;
  const int row0 = (blockIdx.x >> 2) * 16;
  const int j0 = (blockIdx.x & 3) * 64;

  sst[0][lane] = 0.f;
  sst[1][lane] = 0.f;

  f32x4 acc[4];
  #pragma unroll
  for (int jt = 0; jt < 4; ++jt) {
    float bv = b2[j0 + jt*16 + m16];
    acc[jt] = (f32x4){bv, bv, bv, bv};
  }
  #pragma unroll
  for (int ks = 0; ks < 8; ++ks) {
    short8 af = *reinterpret_cast<const short8*>(
        h1g + (size_t)(row0 + m16)*256 + ks*32 + ko);
    short8 bf[4];
    #pragma unroll
    for (int jt = 0; jt < 4; ++jt)
      bf[jt] = *reinterpret_cast<const short8*>(
          W2T + (size_t)(j0 + jt*16 + m16)*256 + ks*32 + ko);
    #pragma unroll
    for (int jt = 0; jt < 4; ++jt)
      acc[jt] = __builtin_amdgcn_mfma_f32_16x16x32_bf16(af, bf[jt], acc[jt], 0, 0, 0);
  }
  #pragma unroll
  for (int jt = 0; jt < 4; ++jt) {
    float ps = 0.f, pq = 0.f;
    #pragma unroll
    for (int r = 0; r < 4; ++r) {
      float hv = eluf(acc[jt][r]);
      hls[quad*4 + r][jt*16 + m16] = __float2bfloat16(hv);
      ps += hv; pq += hv * hv;
    }
    atomicAdd(&sst[0][jt*16 + m16], ps);
    atomicAdd(&sst[1][jt*16 + m16], pq);
  }
  atomicAdd(&stats[j0 + lane], sst[0][lane]);
  atomicAdd(&stats[256 + j0 + lane], sst[1][lane]);
  #pragma unroll
  for (int i = 0; i < 2; ++i) {
    int u = i*64 + lane;
    int r = u >> 3, c = (u & 7) * 8;
    *reinterpret_cast<uint4*>(m2 + (size_t)(row0 + r)*256 + j0 + c) =
        *reinterpret_cast<const uint4*>(&hls[r][c]);
  }
}

// ================= head fuse layer: single-wave, grid 256 ======================
__global__ __launch_bounds__(64) void k_hf(
    const __hip_bfloat16* __restrict__ xg,    // 1024 x 256
    const __hip_bfloat16* __restrict__ m2,    // 1024 x 256
    const float* __restrict__ stM,
    const float* __restrict__ gam,
    const float* __restrict__ bet,
    const __hip_bfloat16* __restrict__ WfT,   // 256 x 512
    const float* __restrict__ bfv,
    __hip_bfloat16* __restrict__ fg) {        // 1024 x 256
  __shared__ alignas(16) __hip_bfloat16 hls[16][72];
  __shared__ float bnA[256], bnC[256];
  const int lane = threadIdx.x;
  const int m16 = lane & 15, quad = lane >> 4;
  const int ko = quad * 8;
  const int row0 = (blockIdx.x >> 2) * 16;
  const int j0 = (blockIdx.x & 3) * 64;

  {  // BN affine table: 4 entries per lane
    const float inv = 1.f / (float)NROWS;
    #pragma unroll
    for (int j = 0; j < 4; ++j) {
      int k = lane*4 + j;
      float mean = stM[k] * inv;
      float var  = fmaxf(stM[256 + k] * inv - mean*mean, 0.f);
      float am = gam[k] * rsqrtf(var + 1e-5f);
      bnA[k] = am;
      bnC[k] = bet[k] - mean * am;
    }
  }

  f32x4 acc[4];
  #pragma unroll
  for (int jt = 0; jt < 4; ++jt) {
    float bv = bfv[j0 + jt*16 + m16];
    acc[jt] = (f32x4){bv, bv, bv, bv};
  }
  #pragma unroll
  for (int ks = 0; ks < 16; ++ks) {
    short8 af;
    if (ks < 8) {
      af = *reinterpret_cast<const short8*>(
          xg + (size_t)(row0 + m16)*256 + ks*32 + ko);
    } else {
      int k0 = (ks - 8)*32 + ko;
      union { uint4 u; __hip_bfloat16 h[8]; } v;
      v.u = *reinterpret_cast<const uint4*>(m2 + (size_t)(row0 + m16)*256 + k0);
      union { short8 s8; __hip_bfloat16 h[8]; } o;
      #pragma unroll
      for (int j = 0; j < 8; ++j)
        o.h[j] = __float2bfloat16(bnA[k0+j] * __bfloat162float(v.h[j]) + bnC[k0+j]);
      af = o.s8;
    }
    short8 bf[4];
    #pragma unroll
    for (int jt = 0; jt < 4; ++jt)
      bf[jt] = *reinterpret_cast<const short8*>(
          WfT + (size_t)(j0 + jt*16 + m16)*512 + ks*32 + ko);
    #pragma unroll
    for (int jt = 0; jt < 4; ++jt)
      acc[jt] = __builtin_amdgcn_mfma_f32_16x16x32_bf16(af, bf[jt], acc[jt], 0, 0, 0);
  }
  #pragma unroll
  for (int jt = 0; jt < 4; ++jt)
    #pragma unroll
    for (int r = 0; r < 4; ++r)
      hls[quad*4 + r][jt*16 + m16] = __float2bfloat16(acc[jt][r]);   // no activation
  #pragma unroll
  for (int i = 0; i < 2; ++i) {
    int u = i*64 + lane;
    int r = u >> 3, c = (u & 7) * 8;
    *reinterpret_cast<uint4*>(fg + (size_t)(row0 + r)*256 + j0 + c) =
        *reinterpret_cast<const uint4*>(&hls[r][c]);
  }
}

// ================= pred + cumsum: single-wave, grid 64 =========================
__global__ __launch_bounds__(64) void k_pred(
    const __hip_bfloat16* __restrict__ fg,    // 1024 x 256
    const __hip_bfloat16* __restrict__ WpT,   // 64 x 256 (zero-padded)
    const float* __restrict__ bp,
    const float* __restrict__ centers,
    float* __restrict__ out) {
  __shared__ float rl[16][68];
  const int lane = threadIdx.x;
  const int m16 = lane & 15, quad = lane >> 4;
  const int ko = quad * 8;
  const int row0 = blockIdx.x * 16;

  f32x4 acc[4];
  #pragma unroll
  for (int jt = 0; jt < 4; ++jt) {
    int c = jt*16 + m16;
    float bv = (c < 60) ? bp[c] : 0.f;
    acc[jt] = (f32x4){bv, bv, bv, bv};
  }
  #pragma unroll
  for (int ks = 0; ks < 8; ++ks) {
    short8 af = *reinterpret_cast<const short8*>(
        fg + (size_t)(row0 + m16)*256 + ks*32 + ko);
    short8 bf[4];
    #pragma unroll
    for (int jt = 0; jt < 4; ++jt)
      bf[jt] = *reinterpret_cast<const short8*>(
          WpT + (size_t)(jt*16 + m16)*256 + ks*32 + ko);
    #pragma unroll
    for (int jt = 0; jt < 4; ++jt)
      acc[jt] = __builtin_amdgcn_mfma_f32_16x16x32_bf16(af, bf[jt], acc[jt], 0, 0, 0);
  }
  #pragma unroll
  for (int jt = 0; jt < 4; ++jt) {
    int c = jt*16 + m16;
    #pragma unroll
    for (int r = 0; r < 4; ++r) {
      int lr = quad*4 + r;
      rl[lr][c] = acc[jt][r];
      if (c < 60) out[(size_t)(row0 + lr)*60 + c] = acc[jt][r];
    }
  }
  // single wave: cumsum reads rl after compiler-inserted lgkmcnt wait
  if (lane < 32) {
    int lr = lane >> 1, xy = lane & 1;
    int grow = row0 + lr;
    float run = centers[(size_t)(grow*PREVN + 5)*2 + xy];
    #pragma unroll
    for (int p = 0; p < PREDN; ++p) {
      run += rl[lr][2*p + xy];
      out[61440 + (size_t)grow*60 + 2*p + xy] = run;
    }
  }
}

extern "C" void kernel_launch(void* const* d_in, const int* in_sizes, int n_in,
                              void* d_out, int out_size, void* d_ws, size_t ws_size,
                              hipStream_t stream) {
  const float* centers = (const float*)d_in[0];
  float* ws = (float*)d_ws;
  __hip_bfloat16* wb = (__hip_bfloat16*)(ws + F32_END);
  __hip_bfloat16* xrs = (__hip_bfloat16*)(ws + OFF_XRS);

  const float* W_traj = (const float*)d_in[3];
  const float* b_traj = (const float*)d_in[4];
  const float* n2e_b1 = (const float*)d_in[6];
  const float* n2e_b2 = (const float*)d_in[8];
  const float* n2e_g  = (const float*)d_in[9];
  const float* n2e_be = (const float*)d_in[10];
  const float* e2n_b1 = (const float*)d_in[12];
  const float* e2n_b2 = (const float*)d_in[14];
  const float* e2n_g  = (const float*)d_in[15];
  const float* e2n_be = (const float*)d_in[16];
  const float* b_fuse = (const float*)d_in[18];
  const float* b_pred = (const float*)d_in[20];

  PrepArgs pa;
  pa.n2e_W1 = (const float*)d_in[5];  pa.n2e_W2 = (const float*)d_in[7];
  pa.e2n_W1 = (const float*)d_in[11]; pa.e2n_W2 = (const float*)d_in[13];
  pa.W_fuse = (const float*)d_in[17]; pa.W_pred = (const float*)d_in[19];
  pa.ws = ws;
  pa.w1te = wb + BO_W1TE; pa.w2te = wb + BO_W2TE;
  pa.w1tn = wb + BO_W1TN; pa.w2tn = wb + BO_W2TN;
  pa.wft = wb + BO_WFT;   pa.wpt = wb + BO_WPT;

  k_prep<<<200, 256, 0, stream>>>(pa);
  k_xrs<<<64, 256, 0, stream>>>(centers, W_traj, b_traj, wb + BO_W1TE, n2e_b1,
                                xrs, wb + BO_XG);
  k_mlp6<<<EROWS/64, 256, 0, stream>>>(xrs, wb + BO_W2TE, n2e_b2, wb + BO_E2,
                                       ws + OFF_STATS_E);
  k_agg2<<<2*NROWS, 1024, 0, stream>>>(wb + BO_E2, ws + OFF_STATS_E, n2e_g, n2e_be,
                                       wb + BO_NODES);
  k_n1<<<256, 64, 0, stream>>>(wb + BO_NODES, wb + BO_W1TN, e2n_b1, wb + BO_H1G);
  k_n2<<<256, 64, 0, stream>>>(wb + BO_H1G, wb + BO_W2TN, e2n_b2, wb + BO_M2,
                               ws + OFF_STATS_M);
  k_hf<<<256, 64, 0, stream>>>(wb + BO_XG, wb + BO_M2, ws + OFF_STATS_M,
                               e2n_g, e2n_be, wb + BO_WFT, b_fuse, wb + BO_FG);
  k_pred<<<64, 64, 0, stream>>>(wb + BO_FG, wb + BO_WPT, b_pred, centers,
                                (float*)d_out);
}